// Round 11
// baseline (274.524 us; speedup 1.0000x reference)
//
#include <hip/hip_runtime.h>
#include <math.h>

typedef __attribute__((ext_vector_type(8))) short s16x8;
typedef __attribute__((ext_vector_type(4))) float f32x4;
typedef __attribute__((ext_vector_type(16))) float f32x16;

#define N_ROWS 2048
#define D_DIM  128
#define N_CLS  100000
#define N_TILES 782              // ceil(100000/128)
#define N_PAD   96.0f            // 782*128 - 100000 pad classes, each contributes exp2(0)=1
#define S_SCALE 64.0f
#define S_LOG2E 92.33248261689366f   // 64 * log2(e)
#define EPS_F   1e-7f
#define COS_M   0.8775825618903728f  // cos(0.5)
#define SIN_M   0.479425538604203f   // sin(0.5)

#if __has_builtin(__builtin_amdgcn_exp2f)
#define EXP2F(x) __builtin_amdgcn_exp2f(x)
#else
#define EXP2F(x) exp2f(x)
#endif

#define ZERO16 {0.f,0.f,0.f,0.f,0.f,0.f,0.f,0.f,0.f,0.f,0.f,0.f,0.f,0.f,0.f,0.f}

__device__ __forceinline__ unsigned int f2bf1(float f) {
    unsigned int u = __float_as_uint(f);
    return (u + 0x7FFFu + ((u >> 16) & 1u)) >> 16;   // RNE
}
__device__ __forceinline__ unsigned int f2bf2(float lo, float hi) {
    return f2bf1(lo) | (f2bf1(hi) << 16);
}

// Kernel 1: L2-normalize rows of x -> bf16 in 32x32x16-MFMA B-fragment order,
// PRESCALED by S*log2(e). Fused target logit. 8 threads/row (thread p owns
// k-tile kt=p, 16 floats). xb2 layout: [it(16)][wq(4)][kt(8)][lane(64)] uint4,
// lane = kh*32 + r32 holds row (it*128+wq*32+r32), k = kt*16 + kh*8 + (0..7).
__global__ __launch_bounds__(256)
void k_normalize(const float* __restrict__ x, const float* __restrict__ W,
                 const int* __restrict__ labels,
                 float* __restrict__ tgt, uint4* __restrict__ xb2) {
    const int t = threadIdx.x;
    const int row = blockIdx.x * 32 + (t >> 3);
    const int p = t & 7;              // = kt

    const f32x4* src = (const f32x4*)(x + (size_t)row * D_DIM + p * 16);
    f32x4 v[4];
    float s = 0.f;
    #pragma unroll
    for (int q = 0; q < 4; q++) {
        v[q] = src[q];
        s += v[q][0]*v[q][0] + v[q][1]*v[q][1] + v[q][2]*v[q][2] + v[q][3]*v[q][3];
    }
    s += __shfl_xor(s, 1); s += __shfl_xor(s, 2); s += __shfl_xor(s, 4);
    const float inv = 1.0f / sqrtf(s);

    // fused target-logit dot with W[y] (unscaled, fp32)
    const int y = labels[row];
    const f32x4* wsrc = (const f32x4*)(W + (size_t)y * D_DIM + p * 16);
    float d = 0.f;
    #pragma unroll
    for (int q = 0; q < 4; q++) {
        f32x4 w = wsrc[q];
        d += v[q][0]*w[0] + v[q][1]*w[1] + v[q][2]*w[2] + v[q][3]*w[3];
    }
    d += __shfl_xor(d, 1); d += __shfl_xor(d, 2); d += __shfl_xor(d, 4);
    if (p == 0) tgt[row] = d * inv;

    const float invs = inv * S_LOG2E;  // prescale for the exp2 path
    #pragma unroll
    for (int q = 0; q < 4; q++) {
        v[q][0] *= invs; v[q][1] *= invs; v[q][2] *= invs; v[q][3] *= invs;
    }

    const int it = row >> 7, wq = (row >> 5) & 3, r32 = row & 31;
    #pragma unroll
    for (int kh = 0; kh < 2; kh++) {
        const int idx = it * 2048 + wq * 512 + p * 64 + kh * 32 + r32;
        f32x4 f0 = v[kh * 2], f1 = v[kh * 2 + 1];
        xb2[idx] = make_uint4(f2bf2(f0[0], f0[1]), f2bf2(f0[2], f0[3]),
                              f2bf2(f1[0], f1[1]), f2bf2(f1[2], f1[3]));
    }
}

// One row-tile iteration: 32 MFMA (4 class-tiles x 8 k-tiles, 4-way ILP chains),
// B prefetch for it+1 spread through the kt loop, fully in-lane exp epilogue
// with ONE shfl per iteration and a plain psum store (no atomics).
#define ITBODY(BCUR, BNXT, IT) do {                                           \
    f32x16 acc0 = ZERO16, acc1 = ZERO16, acc2 = ZERO16, acc3 = ZERO16;        \
    _Pragma("unroll")                                                         \
    for (int kt = 0; kt < 8; kt++) {                                          \
        const s16x8 a0 = *(const s16x8*)&Wsh[0 * 512 + kt * 64 + lane];       \
        const s16x8 a1 = *(const s16x8*)&Wsh[1 * 512 + kt * 64 + lane];       \
        const s16x8 a2 = *(const s16x8*)&Wsh[2 * 512 + kt * 64 + lane];       \
        const s16x8 a3 = *(const s16x8*)&Wsh[3 * 512 + kt * 64 + lane];       \
        const s16x8 b_ = *(const s16x8*)&BCUR[kt];                            \
        acc0 = __builtin_amdgcn_mfma_f32_32x32x16_bf16(a0, b_, acc0, 0, 0, 0);\
        acc1 = __builtin_amdgcn_mfma_f32_32x32x16_bf16(a1, b_, acc1, 0, 0, 0);\
        acc2 = __builtin_amdgcn_mfma_f32_32x32x16_bf16(a2, b_, acc2, 0, 0, 0);\
        acc3 = __builtin_amdgcn_mfma_f32_32x32x16_bf16(a3, b_, acc3, 0, 0, 0);\
        if ((IT) + 1 < 16)                                                    \
            BNXT[kt] = bbase[((IT) + 1) * 2048 + kt * 64];                    \
    }                                                                         \
    float sA = 0.f, sB = 0.f;                                                 \
    _Pragma("unroll")                                                         \
    for (int r_ = 0; r_ < 16; r_++) {                                         \
        sA += EXP2F(acc0[r_]) + EXP2F(acc1[r_]);                              \
        sB += EXP2F(acc2[r_]) + EXP2F(acc3[r_]);                              \
    }                                                                         \
    float s_ = sA + sB;                                                       \
    s_ += __shfl_xor(s_, 32);                                                 \
    if (lane < 32) psum[IT][wq * 32 + lane] = s_;                             \
} while (0)

// Kernel 2: one block per 128-class tile; wave wq owns row-quarter wq (32 rows)
// x all 128 classes. A (W tile) in LDS fragment-ordered for 32x32x16; B streams
// from L2-resident xb2, register double-buffered.
__global__ __launch_bounds__(256, 3)
void k_main(const uint4* __restrict__ xb2, const float* __restrict__ W,
            float* __restrict__ rowsum) {
    __shared__ uint4 Wsh[2048];         // 32 KB: [ct(4)][kt(8)][lane(64)]
    __shared__ float psum[16][128];     // 8 KB: [it][row-in-tile]
    const int t = threadIdx.x;
    const int c0 = blockIdx.x * 128;    // class tile base

    // ---- stage + convert W tile, 32x32x16-A-fragment order ----
    #pragma unroll
    for (int m = 0; m < 8; m++) {
        const int idx = m * 256 + t;
        const int ct = idx >> 9, kt = (idx >> 6) & 7, ln = idx & 63;
        const int cls = c0 + ct * 32 + (ln & 31);
        const int k0 = kt * 16 + (ln >> 5) * 8;
        uint4 val = make_uint4(0u, 0u, 0u, 0u);
        if (cls < N_CLS) {
            const f32x4* g = (const f32x4*)(W + (size_t)cls * D_DIM + k0);
            f32x4 f0 = g[0], f1 = g[1];
            val.x = f2bf2(f0[0], f0[1]); val.y = f2bf2(f0[2], f0[3]);
            val.z = f2bf2(f1[0], f1[1]); val.w = f2bf2(f1[2], f1[3]);
        }
        Wsh[idx] = val;
    }
    __syncthreads();

    const int lane = t & 63;
    const int wq = t >> 6;              // row quarter (0..3)
    const uint4* bbase = xb2 + wq * 512 + lane;

    uint4 bP[8], bQ[8];
    #pragma unroll
    for (int kt = 0; kt < 8; kt++) bP[kt] = bbase[kt * 64];

    for (int it = 0; it < 16; it += 2) {
        ITBODY(bP, bQ, it);
        ITBODY(bQ, bP, it + 1);
    }

    // ---- one global-atomic burst per block, after all compute ----
    __syncthreads();
    #pragma unroll
    for (int k = 0; k < 8; k++) {
        const int flat = t + k * 256;
        const int itg = flat >> 7, r = flat & 127;
        atomicAdd(&rowsum[itg * 128 + r], psum[itg][r]);
    }
}

// Kernel 3: per-row loss + mean. Single block. Subtracts the 96 pad-class exps.
__global__ void k_final(const float* __restrict__ rowsum, const float* __restrict__ tgt,
                        float* __restrict__ out) {
    int t = threadIdx.x;
    float lsum = 0.f;
    for (int i = t; i < N_ROWS; i += 256) {
        float tr = tgt[i];
        float tc = fminf(fmaxf(tr, -1.f + EPS_F), 1.f - EPS_F);
        float num = S_SCALE * (tc * COS_M - sqrtf(fmaxf(1.f - tc * tc, 0.f)) * SIN_M);
        float excl = rowsum[i] - N_PAD - __expf(S_SCALE * tr);
        float den = __expf(num) + excl;
        lsum += num - logf(den);
    }
    #pragma unroll
    for (int off = 1; off < 64; off <<= 1) lsum += __shfl_xor(lsum, off);
    __shared__ float wsums[4];
    if ((t & 63) == 0) wsums[t >> 6] = lsum;
    __syncthreads();
    if (t == 0) out[0] = -(wsums[0] + wsums[1] + wsums[2] + wsums[3]) / (float)N_ROWS;
}

extern "C" void kernel_launch(void* const* d_in, const int* in_sizes, int n_in,
                              void* d_out, int out_size, void* d_ws, size_t ws_size,
                              hipStream_t stream) {
    const float* x = (const float*)d_in[0];
    const float* W = (const float*)d_in[1];
    const int* labels = (const int*)d_in[2];
    float* out = (float*)d_out;

    uint4* xb2    = (uint4*)d_ws;                                   // N*D bf16, fragment order
    float* rowsum = (float*)((char*)xb2 + (size_t)N_ROWS * D_DIM * 2);
    float* tgt    = rowsum + N_ROWS;

    hipMemsetAsync(rowsum, 0, N_ROWS * sizeof(float), stream);
    k_normalize<<<N_ROWS / 32, 256, 0, stream>>>(x, W, labels, tgt, xb2);
    k_main<<<N_TILES, 256, 0, stream>>>(xb2, W, rowsum);
    k_final<<<1, 256, 0, stream>>>(rowsum, tgt, out);
}

// Round 12
// 93.666 us; speedup vs baseline: 2.9309x; 2.9309x over previous
//
#include <hip/hip_runtime.h>
#include <math.h>

typedef __attribute__((ext_vector_type(8))) short s16x8;
typedef __attribute__((ext_vector_type(4))) float f32x4;

#define N_ROWS 2048
#define D_DIM  128
#define N_CLS  100000
#define N_TILES 782              // ceil(100000/128)
#define N_PAD   96.0f            // 782*128 - 100000 pad classes, each contributes exp2(0)=1
#define S_SCALE 64.0f
#define S_LOG2E 92.33248261689366f   // 64 * log2(e)
#define EPS_F   1e-7f
#define COS_M   0.8775825618903728f  // cos(0.5)
#define SIN_M   0.479425538604203f   // sin(0.5)

#if __has_builtin(__builtin_amdgcn_exp2f)
#define EXP2F(x) __builtin_amdgcn_exp2f(x)
#else
#define EXP2F(x) exp2f(x)
#endif

__device__ __forceinline__ unsigned int f2bf1(float f) {
    unsigned int u = __float_as_uint(f);
    return (u + 0x7FFFu + ((u >> 16) & 1u)) >> 16;   // RNE
}
__device__ __forceinline__ unsigned int f2bf2(float lo, float hi) {
    return f2bf1(lo) | (f2bf1(hi) << 16);
}

// Kernel 1: L2-normalize rows of x -> bf16 in MFMA-B-fragment order, PRESCALED by
// S*log2(e). Fused target logit tgt[i]. 8 threads/row, 32 rows/block (64 blocks).
__global__ __launch_bounds__(256)
void k_normalize(const float* __restrict__ x, const float* __restrict__ W,
                 const int* __restrict__ labels,
                 float* __restrict__ tgt, uint4* __restrict__ xb2) {
    const int t = threadIdx.x;
    const int row = blockIdx.x * 32 + (t >> 3);
    const int p = t & 7;              // 8 threads per row, 16 floats each

    const f32x4* src = (const f32x4*)(x + (size_t)row * D_DIM + p * 16);
    f32x4 v[4];
    float s = 0.f;
    #pragma unroll
    for (int q = 0; q < 4; q++) {
        v[q] = src[q];
        s += v[q][0]*v[q][0] + v[q][1]*v[q][1] + v[q][2]*v[q][2] + v[q][3]*v[q][3];
    }
    s += __shfl_xor(s, 1); s += __shfl_xor(s, 2); s += __shfl_xor(s, 4);
    const float inv = 1.0f / sqrtf(s);

    // fused target-logit dot with W[y] (unscaled, fp32)
    const int y = labels[row];
    const f32x4* wsrc = (const f32x4*)(W + (size_t)y * D_DIM + p * 16);
    float d = 0.f;
    #pragma unroll
    for (int q = 0; q < 4; q++) {
        f32x4 w = wsrc[q];
        d += v[q][0]*w[0] + v[q][1]*w[1] + v[q][2]*w[2] + v[q][3]*w[3];
    }
    d += __shfl_xor(d, 1); d += __shfl_xor(d, 2); d += __shfl_xor(d, 4);
    if (p == 0) tgt[row] = d * inv;

    const float invs = inv * S_LOG2E;  // prescale for the exp2 path
    #pragma unroll
    for (int q = 0; q < 4; q++) {
        v[q][0] *= invs; v[q][1] *= invs; v[q][2] *= invs; v[q][3] *= invs;
    }

    const int gt = row >> 7, rr = row & 127;
    const int wn = rr >> 6, j = (rr >> 4) & 3, lrr = rr & 15;
    #pragma unroll
    for (int c2 = 0; c2 < 2; c2++) {
        const int ck = p * 2 + c2;
        const int ks = ck >> 2, lk = ck & 3;
        const int idx = gt * 2048 + wn * 1024 + j * 256 + ks * 64 + lk * 16 + lrr;
        f32x4 f0 = v[c2 * 2], f1 = v[c2 * 2 + 1];
        xb2[idx] = make_uint4(f2bf2(f0[0], f0[1]), f2bf2(f0[2], f0[3]),
                              f2bf2(f1[0], f1[1]), f2bf2(f1[2], f1[3]));
    }
}

// 16 MFMA for one phase into ACC0..ACC3 (fresh zero-init accumulate over ks)
#define MFMA16(ACC, BUF) do {                                                 \
    ACC##0 = (f32x4){0.f,0.f,0.f,0.f}; ACC##1 = (f32x4){0.f,0.f,0.f,0.f};     \
    ACC##2 = (f32x4){0.f,0.f,0.f,0.f}; ACC##3 = (f32x4){0.f,0.f,0.f,0.f};     \
    _Pragma("unroll")                                                         \
    for (int ks_ = 0; ks_ < 4; ks_++) {                                       \
        const s16x8 b_ = *(const s16x8*)&BUF[ks_];                            \
        ACC##0 = __builtin_amdgcn_mfma_f32_16x16x32_bf16(a_[ks_][0], b_, ACC##0, 0, 0, 0); \
        ACC##1 = __builtin_amdgcn_mfma_f32_16x16x32_bf16(a_[ks_][1], b_, ACC##1, 0, 0, 0); \
        ACC##2 = __builtin_amdgcn_mfma_f32_16x16x32_bf16(a_[ks_][2], b_, ACC##2, 0, 0, 0); \
        ACC##3 = __builtin_amdgcn_mfma_f32_16x16x32_bf16(a_[ks_][3], b_, ACC##3, 0, 0, 0); \
    }                                                                         \
} while (0)

// Re-issue BUF's loads for row-tile (it+1)
#define RELOAD(BUF, J) do {                                                   \
    if (it < 15) {                                                            \
        _Pragma("unroll")                                                     \
        for (int ks_ = 0; ks_ < 4; ks_++)                                     \
            BUF[ks_] = bbase[(it + 1) * 2048 + (J) * 256 + ks_ * 64];         \
    }                                                                         \
} while (0)

// exp2-epilogue for the PREVIOUS phase (acc results are >=1 phase old: no stall).
// wm=0/1 halves merge via fire-and-forget LDS atomicAdd (nothing waits on it).
#define EXPST(ACC, ITE, JE) do {                                              \
    f32x4 pv;                                                                 \
    _Pragma("unroll")                                                         \
    for (int r_ = 0; r_ < 4; r_++)                                            \
        pv[r_] = (EXP2F(ACC##0[r_]) + EXP2F(ACC##1[r_]))                      \
               + (EXP2F(ACC##2[r_]) + EXP2F(ACC##3[r_]));                     \
    float pj = (pv[0] + pv[1]) + (pv[2] + pv[3]);                             \
    pj += __shfl_xor(pj, 16);                                                 \
    pj += __shfl_xor(pj, 32);                                                 \
    if ((lane >> 4) == 0)                                                     \
        atomicAdd(&psum[ITE][wn * 64 + (JE) * 16 + lr], pj);                  \
} while (0)

// Kernel 2: one block per 128-class tile; 16 row-tile iterations; acc ping-pong
// software pipeline. LDS = 32KB (Wsh) + 8KB (psum) = 40KB -> 4 blocks/CU by LDS,
// so all 782 blocks are co-resident (zero second dispatch round). launch_bounds
// stays (256,3) so the register allocator keeps the 170-VGPR budget (no spill).
__global__ __launch_bounds__(256, 3)
void k_main(const uint4* __restrict__ xb2, const float* __restrict__ W,
            float* __restrict__ rowsum) {
    __shared__ uint4 Wsh[2048];         // 32 KB, fragment-ordered bf16 W tile
    __shared__ float psum[16][128];     // 8 KB: [it][row-in-tile]
    const int t = threadIdx.x;
    const int c0 = blockIdx.x * 128;    // class tile base

    // zero psum (visibility covered by the staging barrier below)
    #pragma unroll
    for (int k = 0; k < 8; k++) ((float*)psum)[t + k * 256] = 0.f;

    // ---- stage + convert W tile, fragment order (once per block) ----
    #pragma unroll
    for (int m = 0; m < 8; m++) {
        const int idx = m * 256 + t;
        const int flr = idx & 15, lk = (idx >> 4) & 3;
        const int ks = (idx >> 6) & 3, fi = (idx >> 8) & 3, fwm = idx >> 10;
        const int cls = c0 + fwm * 64 + fi * 16 + flr;
        const int k0 = (ks * 4 + lk) * 8;
        uint4 val = make_uint4(0u, 0u, 0u, 0u);
        if (cls < N_CLS) {
            const f32x4* g = (const f32x4*)(W + (size_t)cls * D_DIM + k0);
            f32x4 f0 = g[0], f1 = g[1];
            val.x = f2bf2(f0[0], f0[1]); val.y = f2bf2(f0[2], f0[3]);
            val.z = f2bf2(f1[0], f1[1]); val.w = f2bf2(f1[2], f1[3]);
        }
        Wsh[idx] = val;
    }
    __syncthreads();

    const int lane = t & 63;
    const int wid = t >> 6;
    const int wm = wid >> 1;            // class half (0/1)
    const int wn = wid & 1;             // x-row half (0/1)
    const int lr = lane & 15;
    const uint4* bbase = xb2 + wn * 1024 + lane;

    uint4 b0[4], b1[4], b2[4], b3[4];
    s16x8 a_[4][4];
    f32x4 accA0, accA1, accA2, accA3;
    f32x4 accB0, accB1, accB2, accB3;

    // B prologue: all 4 fragments of it=0
    #pragma unroll
    for (int ks = 0; ks < 4; ks++) {
        b0[ks] = bbase[0 * 256 + ks * 64];
        b1[ks] = bbase[1 * 256 + ks * 64];
        b2[ks] = bbase[2 * 256 + ks * 64];
        b3[ks] = bbase[3 * 256 + ks * 64];
    }

    for (int it = 0; it < 16; it++) {
        // A fragments for this W half-tile (LDS, conflict-free b128 reads)
        #pragma unroll
        for (int ks = 0; ks < 4; ks++)
            #pragma unroll
            for (int i = 0; i < 4; i++)
                a_[ks][i] = *(const s16x8*)&Wsh[wm * 1024 + i * 256 + ks * 64 + lane];
        // deferred epilogue of previous it's j3 covers the lgkmcnt on a_ reads
        if (it) EXPST(accB, it - 1, 3);
        MFMA16(accA, b0);  RELOAD(b0, 0);
        MFMA16(accB, b1);  RELOAD(b1, 1);  EXPST(accA, it, 0);
        MFMA16(accA, b2);  RELOAD(b2, 2);  EXPST(accB, it, 1);
        MFMA16(accB, b3);  RELOAD(b3, 3);  EXPST(accA, it, 2);
    }
    EXPST(accB, 15, 3);

    // ---- one global-atomic burst per block, after all compute ----
    __syncthreads();
    #pragma unroll
    for (int k = 0; k < 8; k++) {
        const int flat = t + k * 256;
        const int it = flat >> 7, r = flat & 127;
        atomicAdd(&rowsum[it * 128 + r], psum[it][r]);
    }
}

// Kernel 3: per-row loss + mean. Single block. Subtracts the 96 pad-class exps.
__global__ void k_final(const float* __restrict__ rowsum, const float* __restrict__ tgt,
                        float* __restrict__ out) {
    int t = threadIdx.x;
    float lsum = 0.f;
    for (int i = t; i < N_ROWS; i += 256) {
        float tr = tgt[i];
        float tc = fminf(fmaxf(tr, -1.f + EPS_F), 1.f - EPS_F);
        float num = S_SCALE * (tc * COS_M - sqrtf(fmaxf(1.f - tc * tc, 0.f)) * SIN_M);
        float excl = rowsum[i] - N_PAD - __expf(S_SCALE * tr);
        float den = __expf(num) + excl;
        lsum += num - logf(den);
    }
    #pragma unroll
    for (int off = 1; off < 64; off <<= 1) lsum += __shfl_xor(lsum, off);
    __shared__ float wsums[4];
    if ((t & 63) == 0) wsums[t >> 6] = lsum;
    __syncthreads();
    if (t == 0) out[0] = -(wsums[0] + wsums[1] + wsums[2] + wsums[3]) / (float)N_ROWS;
}

extern "C" void kernel_launch(void* const* d_in, const int* in_sizes, int n_in,
                              void* d_out, int out_size, void* d_ws, size_t ws_size,
                              hipStream_t stream) {
    const float* x = (const float*)d_in[0];
    const float* W = (const float*)d_in[1];
    const int* labels = (const int*)d_in[2];
    float* out = (float*)d_out;

    uint4* xb2    = (uint4*)d_ws;                                   // N*D bf16, fragment order
    float* rowsum = (float*)((char*)xb2 + (size_t)N_ROWS * D_DIM * 2);
    float* tgt    = rowsum + N_ROWS;

    hipMemsetAsync(rowsum, 0, N_ROWS * sizeof(float), stream);
    k_normalize<<<N_ROWS / 32, 256, 0, stream>>>(x, W, labels, tgt, xb2);
    k_main<<<N_TILES, 256, 0, stream>>>(xb2, W, rowsum);
    k_final<<<1, 256, 0, stream>>>(rowsum, tgt, out);
}